// Round 7
// baseline (1026.664 us; speedup 1.0000x reference)
//
#include <hip/hip_runtime.h>
#include <hip/hip_bf16.h>
#include <math.h>

#define NPTS 4096
#define CIN 64
#define COUT 64
#define BATCH 8
#define KNN 20
#define NCHUNK 4
#define CHUNK (NPTS / NCHUNK)
#define TILE 64
#define NTILE (CHUNK / TILE)

// ---------------------------------------------------------------------------
// K0: transpose x -> xT[b][n][c], xx[b][n] = sum_c x^2, and the two small
// GEMMs u[b][n][o] = sum_c (W[o,c]-W[o,64+c])*x[b,c,n],
//       v[b][n][o] = sum_c  W[o,64+c]      *x[b,c,n]
// (h[b,o,n,k] = u[b,n,o] + v[b,idx[b,n,k],o] by linearity of the edge-conv.)
// ---------------------------------------------------------------------------
__global__ __launch_bounds__(256) void k_prep(const float* __restrict__ x,
                                              const float* __restrict__ W,
                                              float* __restrict__ xT,
                                              float* __restrict__ xx,
                                              float* __restrict__ u,
                                              float* __restrict__ v) {
    __shared__ float xs[64][65];   // [c][j], padded: transpose read is conflict-free
    __shared__ float wd[64][64];   // [c][o] = W1 - W2
    __shared__ float wv[64][64];   // [c][o] = W2
    const int t = threadIdx.x;
    const int b = blockIdx.y;
    const int n0 = blockIdx.x * 64;

    const float* xb = x + (size_t)b * CIN * NPTS;
#pragma unroll
    for (int i = 0; i < 16; ++i) {          // load x tile, coalesced per c-row
        int flat = t + 256 * i;             // 4096 elements
        int c = flat >> 6, j = flat & 63;
        xs[c][j] = xb[(size_t)c * NPTS + n0 + j];
    }
#pragma unroll
    for (int i = 0; i < 16; ++i) {          // load/transform W (32 KB, L2-cached)
        int flat = t + 256 * i;
        int o = flat & 63, c = flat >> 6;
        float w1 = W[o * 128 + c];
        float w2 = W[o * 128 + 64 + c];
        wd[c][o] = w1 - w2;
        wv[c][o] = w2;
    }
    __syncthreads();

#pragma unroll
    for (int i = 0; i < 16; ++i) {          // write xT, coalesced over c
        int flat = t + 256 * i;
        int j = flat >> 6, c = flat & 63;
        xT[((size_t)b * NPTS + n0 + j) * 64 + c] = xs[c][j];
    }
    if (t < 64) {                           // xx: sequential over c
        float s = 0.f;
#pragma unroll
        for (int c = 0; c < 64; ++c) { float a = xs[c][t]; s += a * a; }
        xx[b * NPTS + n0 + t] = s;
    }

    // u, v: each thread owns channel o = t&63 for 16 point-columns j = (t>>6)+4i
    const int o = t & 63, jb = t >> 6;
    float au[16], av[16];
#pragma unroll
    for (int i = 0; i < 16; ++i) { au[i] = 0.f; av[i] = 0.f; }
    for (int c = 0; c < 64; ++c) {
        float a = wd[c][o];                 // consecutive o -> conflict-free (2-way, free)
        float p = wv[c][o];
#pragma unroll
        for (int i = 0; i < 16; ++i) {
            float xc = xs[c][jb + 4 * i];   // wave-uniform -> LDS broadcast
            au[i] += a * xc;
            av[i] += p * xc;
        }
    }
#pragma unroll
    for (int i = 0; i < 16; ++i) {
        int j = jb + 4 * i;
        size_t base = ((size_t)b * NPTS + n0 + j) * 64 + o;
        u[base] = au[i];                    // coalesced over o
        v[base] = av[i];
    }
}

// ---------------------------------------------------------------------------
// K1: fused distance + top-20, LDS-staged candidate stream.
// R6/R7 changes vs R5 (selection semantics bit-identical):
//  (a) __launch_bounds__(256,1): R3/R5 caps made the allocator park
//      vals/idxs in the AGPR half of the unified file (VGPR_Count=76 =
//      row4+temps only) -> v_accvgpr_read/write round-trips in the chain
//      every candidate (~360 VALU inst/cand measured vs ~150 modeled).
//      Open cap -> whole working set (~170) in arch VGPRs. Grid is 512
//      blocks = 2/CU regardless, so the bound costs no occupancy.
//  (b) vals/idxs pinned with the empty-asm trick that kept row4 resident.
//  (c) bool c[20] -> rolling carry (cj/cjm1): level j uses compares of old
//      vals[j] (carried from level j+1) and old vals[j-1]; 19 fewer live
//      regs, same compare count, identical selection.
// ---------------------------------------------------------------------------
__global__ __launch_bounds__(256, 1) void k_knn(const float* __restrict__ xT,
                                                const float* __restrict__ xx,
                                                float* __restrict__ cval,
                                                int* __restrict__ cidx) {
    __shared__ float cb[TILE * 64];         // 64 cands x 64 ch = 16 KB
    __shared__ float xxs[CHUNK];            // 4 KB
    const int t = threadIdx.x;
    const int bid = blockIdx.x + 16 * (blockIdx.y + NCHUNK * blockIdx.z);
    const int b = bid & 7;                  // XCD id under hw round-robin
    const int slot = bid >> 3;              // 0..63
    const int chunk = slot & (NCHUNK - 1);  // 0..3
    const int rowgrp = slot >> 2;           // 0..15
    const int n = rowgrp * 256 + t;
    const int m0 = chunk * CHUNK;

    const float* xTb = xT + (size_t)b * NPTS * 64;

    // xx chunk -> LDS (published by the tile-0 barrier below)
#pragma unroll
    for (int r = 0; r < 4; ++r)
        xxs[t + 256 * r] = xx[b * NPTS + m0 + t + 256 * r];

    // row -> registers, pinned (compiler otherwise remats the global loads)
    float4 row4[16];
    const float4* rp = (const float4*)(xTb + (size_t)n * 64);
#pragma unroll
    for (int q = 0; q < 16; ++q) row4[q] = rp[q];
#pragma unroll
    for (int q = 0; q < 16; ++q) {
        asm volatile("" : "+v"(row4[q].x), "+v"(row4[q].y),
                          "+v"(row4[q].z), "+v"(row4[q].w));
    }

    float vals[KNN];
    int   idxs[KNN];
#pragma unroll
    for (int k = 0; k < KNN; ++k) { vals[k] = -INFINITY; idxs[k] = -1; }
#pragma unroll
    for (int k = 0; k < KNN; ++k) {         // pin in arch VGPRs
        asm volatile("" : "+v"(vals[k]), "+v"(idxs[k]));
    }

    // stage tile 0 into registers
    const float4* gt0 = (const float4*)(xTb + (size_t)m0 * 64);
    float4 st0 = gt0[t], st1 = gt0[t + 256], st2 = gt0[t + 512], st3 = gt0[t + 768];

    for (int T = 0; T < NTILE; ++T) {
        __syncthreads();                    // all waves done reading cb (tile T-1)
        ((float4*)cb)[t      ] = st0;       // publish tile T
        ((float4*)cb)[t + 256] = st1;
        ((float4*)cb)[t + 512] = st2;
        ((float4*)cb)[t + 768] = st3;
        __syncthreads();
        // issue next tile's loads NOW; they complete during the compute phase
        int Tn = (T + 1 < NTILE) ? T + 1 : T;   // last iter: dummy reload
        const float4* gn = (const float4*)(xTb + (size_t)(m0 + Tn * TILE) * 64);
        st0 = gn[t]; st1 = gn[t + 256]; st2 = gn[t + 512]; st3 = gn[t + 768];

#pragma unroll 2
        for (int mm = 0; mm < TILE; ++mm) {
            const float4* cp = (const float4*)(cb + mm * 64);
            float4 acc = make_float4(0.f, 0.f, 0.f, 0.f);
#pragma unroll
            for (int q = 0; q < 16; ++q) {
                float4 c4 = cp[q];          // uniform addr -> LDS broadcast
                acc.x += row4[q].x * c4.x;
                acc.y += row4[q].y * c4.y;
                acc.z += row4[q].z * c4.z;
                acc.w += row4[q].w * c4.w;
            }
            float inner = (acc.x + acc.y) + (acc.z + acc.w);
            float d = 2.f * inner - xxs[T * TILE + mm];
            const int midx = m0 + T * TILE + mm;
            bool cj = (vals[KNN - 1] >= d);             // old vals[19]
#pragma unroll
            for (int j = KNN - 1; j >= 1; --j) {
                bool cjm1 = (vals[j - 1] >= d);         // old vals[j-1]
                vals[j] = __builtin_amdgcn_fmed3f(d, vals[j - 1], vals[j]);
                idxs[j] = cj ? idxs[j] : (cjm1 ? midx : idxs[j - 1]);
                cj = cjm1;
            }
            vals[0] = fmaxf(vals[0], d);
            idxs[0] = cj ? idxs[0] : midx;
        }
    }

    size_t rbase = ((size_t)(b * NPTS + n) * NCHUNK + chunk) * KNN;
#pragma unroll
    for (int k = 0; k < KNN; ++k) { cval[rbase + k] = vals[k]; cidx[rbase + k] = idxs[k]; }
}

// ---------------------------------------------------------------------------
// K2: K-way merge of the per-chunk sorted top-20 lists. All array indexing is
// compile-time (p[c], c unrolled) -> registers, no scratch. Strict '>' keeps
// the lowest chunk on ties (chunks cover ascending m) = lowest-index-first.
// ---------------------------------------------------------------------------
__global__ __launch_bounds__(256) void k_merge(const float* __restrict__ cval,
                                               const int* __restrict__ cidx,
                                               int* __restrict__ idxf) {
    const int r = blockIdx.x * 256 + threadIdx.x;   // 0..B*N-1
    const float* v0 = cval + (size_t)r * (NCHUNK * KNN);
    const int*   i0 = cidx + (size_t)r * (NCHUNK * KNN);
    int p[NCHUNK];
#pragma unroll
    for (int c = 0; c < NCHUNK; ++c) p[c] = 0;
    int* op = idxf + (size_t)r * KNN;
    for (int k = 0; k < KNN; ++k) {
        float best = -INFINITY; int besti = 0, bc = 0;
#pragma unroll
        for (int c = 0; c < NCHUNK; ++c) {
            float hv = v0[c * KNN + p[c]];          // L1-cached re-reads
            int   hi = i0[c * KNN + p[c]];
            bool g = hv > best;
            best = g ? hv : best;
            besti = g ? hi : besti;
            bc = g ? c : bc;
        }
        op[k] = besti;
#pragma unroll
        for (int c = 0; c < NCHUNK; ++c) p[c] += (bc == c);
    }
}

// ---------------------------------------------------------------------------
// K4: single gather pass: h = u[n][o] + v[m][o]; accumulate sum/sumsq per
// channel (block partials, no atomics -> deterministic) and per-(n,o) max/min.
// Wave = 64 lanes = 64 channels; v rows are 256 B coalesced L2-resident reads.
// ---------------------------------------------------------------------------
__global__ __launch_bounds__(256) void k_gather(const float* __restrict__ u,
                                                const float* __restrict__ v,
                                                const int* __restrict__ idxf,
                                                float* __restrict__ hmax,
                                                float* __restrict__ hmin,
                                                float* __restrict__ part) {
    const int t = threadIdx.x;
    const int o = t & 63, w = t >> 6;
    const int b = blockIdx.y;
    const int n0 = blockIdx.x * 64;
    const float* vb = v + (size_t)b * NPTS * 64;
    float su = 0.f, sq = 0.f;
    for (int r = 0; r < 16; ++r) {
        int n = n0 + w + 4 * r;
        size_t nb = (size_t)b * NPTS + n;
        float hu = u[nb * 64 + o];
        const int* ip = idxf + nb * KNN;    // wave-uniform reads
        float mx = -INFINITY, mn = INFINITY;
#pragma unroll 4
        for (int k = 0; k < KNN; ++k) {
            int m = ip[k];
            float h = hu + vb[(size_t)m * 64 + o];
            mx = fmaxf(mx, h);
            mn = fminf(mn, h);
            su += h;
            sq += h * h;
        }
        hmax[nb * 64 + o] = mx;
        hmin[nb * 64 + o] = mn;
    }
    __shared__ float red[4][128];
    red[w][o] = su;
    red[w][64 + o] = sq;
    __syncthreads();
    if (t < 128) {
        float s = red[0][t] + red[1][t] + red[2][t] + red[3][t];
        part[(size_t)(blockIdx.y * 64 + blockIdx.x) * 128 + t] = s;
    }
}

// ---------------------------------------------------------------------------
// K5: reduce 512 block partials -> mean/var -> fused scale/shift.
// ---------------------------------------------------------------------------
__global__ __launch_bounds__(256) void k_stats(const float* __restrict__ part,
                                               const float* __restrict__ gamma,
                                               const float* __restrict__ beta,
                                               float* __restrict__ ab) {
    __shared__ float rs[4][64], rq[4][64];
    const int t = threadIdx.x;
    const int o = t & 63, sl = t >> 6;      // 4 slices of 128 rows
    float s = 0.f, q = 0.f;
    for (int r = sl; r < 512; r += 4) {
        s += part[r * 128 + o];
        q += part[r * 128 + 64 + o];
    }
    rs[sl][o] = s; rq[sl][o] = q;
    __syncthreads();
    if (t < 64) {
        float ss = rs[0][t] + rs[1][t] + rs[2][t] + rs[3][t];
        float qq = rq[0][t] + rq[1][t] + rq[2][t] + rq[3][t];
        const float cnt = (float)BATCH * NPTS * KNN;
        float mean = ss / cnt;
        float var = qq / cnt - mean * mean;
        float rstd = rsqrtf(var + 1e-5f);
        float a = gamma[t] * rstd;
        ab[t] = a;
        ab[64 + t] = beta[t] - mean * a;
    }
}

// ---------------------------------------------------------------------------
// K6: epilogue. Monotone affine+LeakyReLU => max over k is at hmax (scale>=0)
// or hmin (scale<0). LDS transpose for coalesced out[b][o][n] writes.
// ---------------------------------------------------------------------------
__global__ __launch_bounds__(256) void k_out(const float* __restrict__ hmax,
                                             const float* __restrict__ hmin,
                                             const float* __restrict__ ab,
                                             float* __restrict__ out) {
    __shared__ float ts[64][65];
    const int t = threadIdx.x;
    const int b = blockIdx.y;
    const int n0 = blockIdx.x * 64;
#pragma unroll
    for (int i = 0; i < 16; ++i) {
        int flat = t + 256 * i;
        int j = flat >> 6, o = flat & 63;
        size_t nb = ((size_t)b * NPTS + n0 + j) * 64 + o;
        float a = ab[o], sh = ab[64 + o];
        float hval = (a >= 0.f) ? hmax[nb] : hmin[nb];
        float val = a * hval + sh;
        val = (val >= 0.f) ? val : 0.2f * val;
        ts[o][j] = val;
    }
    __syncthreads();
#pragma unroll
    for (int i = 0; i < 16; ++i) {
        int flat = t + 256 * i;
        int o = flat >> 6, j = flat & 63;
        out[((size_t)b * 64 + o) * NPTS + n0 + j] = ts[o][j];
    }
}

// ---------------------------------------------------------------------------
extern "C" void kernel_launch(void* const* d_in, const int* in_sizes, int n_in,
                              void* d_out, int out_size, void* d_ws, size_t ws_size,
                              hipStream_t stream) {
    const float* x     = (const float*)d_in[0];   // (8, 64, 4096)
    const float* W     = (const float*)d_in[1];   // (64, 128)
    const float* gamma = (const float*)d_in[2];   // (64,)
    const float* beta  = (const float*)d_in[3];   // (64,)
    float* out = (float*)d_out;                   // (8, 64, 4096)

    float* ws = (float*)d_ws;
    const size_t BN = (size_t)BATCH * NPTS;       // 32768
    size_t off = 0;
    float* xT   = ws + off; off += BN * 64;
    float* xx   = ws + off; off += BN;
    float* u    = ws + off; off += BN * 64;
    float* v    = ws + off; off += BN * 64;
    float* cval = ws + off; off += BN * NCHUNK * KNN;
    int*   cidx = (int*)(ws + off); off += BN * NCHUNK * KNN;
    int*   idxf = (int*)(ws + off); off += BN * KNN;
    float* hmx  = ws + off; off += BN * 64;
    float* hmn  = ws + off; off += BN * 64;
    float* part = ws + off; off += 512 * 128;
    float* ab   = ws + off; off += 128;
    // total ~16.5M floats (~66 MB), all buffers fully written before read.

    k_prep  <<<dim3(64, BATCH), 256, 0, stream>>>(x, W, xT, xx, u, v);
    k_knn   <<<dim3(16, NCHUNK, BATCH), 256, 0, stream>>>(xT, xx, cval, cidx);
    k_merge <<<dim3((int)(BN / 256)), 256, 0, stream>>>(cval, cidx, idxf);
    k_gather<<<dim3(64, BATCH), 256, 0, stream>>>(u, v, idxf, hmx, hmn, part);
    k_stats <<<1, 256, 0, stream>>>(part, gamma, beta, ab);
    k_out   <<<dim3(64, BATCH), 256, 0, stream>>>(hmx, hmn, ab, out);
}

// Round 8
// 807.946 us; speedup vs baseline: 1.2707x; 1.2707x over previous
//
#include <hip/hip_runtime.h>
#include <hip/hip_bf16.h>
#include <math.h>

#define NPTS 4096
#define CIN 64
#define COUT 64
#define BATCH 8
#define KNN 20
#define NCHUNK 4            // fused fallback path (R5 config)
#define CHUNK (NPTS / NCHUNK)
#define TILE 64
#define NTILE (CHUNK / TILE)
#define NSEL 8              // split path: 8 chunks of 512 candidates
#define SCH (NPTS / NSEL)   // 512
#define NTILE_A (SCH / TILE)// 8 tiles per k_dist block

// ---------------------------------------------------------------------------
// K0: transpose x -> xT[b][n][c], xx[b][n] = sum_c x^2, and the two small
// GEMMs u[b][n][o] = sum_c (W[o,c]-W[o,64+c])*x[b,c,n],
//       v[b][n][o] = sum_c  W[o,64+c]      *x[b,c,n]
// (h[b,o,n,k] = u[b,n,o] + v[b,idx[b,n,k],o] by linearity of the edge-conv.)
// ---------------------------------------------------------------------------
__global__ __launch_bounds__(256) void k_prep(const float* __restrict__ x,
                                              const float* __restrict__ W,
                                              float* __restrict__ xT,
                                              float* __restrict__ xx,
                                              float* __restrict__ u,
                                              float* __restrict__ v) {
    __shared__ float xs[64][65];   // [c][j], padded: transpose read is conflict-free
    __shared__ float wd[64][64];   // [c][o] = W1 - W2
    __shared__ float wv[64][64];   // [c][o] = W2
    const int t = threadIdx.x;
    const int b = blockIdx.y;
    const int n0 = blockIdx.x * 64;

    const float* xb = x + (size_t)b * CIN * NPTS;
#pragma unroll
    for (int i = 0; i < 16; ++i) {          // load x tile, coalesced per c-row
        int flat = t + 256 * i;             // 4096 elements
        int c = flat >> 6, j = flat & 63;
        xs[c][j] = xb[(size_t)c * NPTS + n0 + j];
    }
#pragma unroll
    for (int i = 0; i < 16; ++i) {          // load/transform W (32 KB, L2-cached)
        int flat = t + 256 * i;
        int o = flat & 63, c = flat >> 6;
        float w1 = W[o * 128 + c];
        float w2 = W[o * 128 + 64 + c];
        wd[c][o] = w1 - w2;
        wv[c][o] = w2;
    }
    __syncthreads();

#pragma unroll
    for (int i = 0; i < 16; ++i) {          // write xT, coalesced over c
        int flat = t + 256 * i;
        int j = flat >> 6, c = flat & 63;
        xT[((size_t)b * NPTS + n0 + j) * 64 + c] = xs[c][j];
    }
    if (t < 64) {                           // xx: sequential over c
        float s = 0.f;
#pragma unroll
        for (int c = 0; c < 64; ++c) { float a = xs[c][t]; s += a * a; }
        xx[b * NPTS + n0 + t] = s;
    }

    // u, v: each thread owns channel o = t&63 for 16 point-columns j = (t>>6)+4i
    const int o = t & 63, jb = t >> 6;
    float au[16], av[16];
#pragma unroll
    for (int i = 0; i < 16; ++i) { au[i] = 0.f; av[i] = 0.f; }
    for (int c = 0; c < 64; ++c) {
        float a = wd[c][o];                 // consecutive o -> conflict-free (2-way, free)
        float p = wv[c][o];
#pragma unroll
        for (int i = 0; i < 16; ++i) {
            float xc = xs[c][jb + 4 * i];   // wave-uniform -> LDS broadcast
            au[i] += a * xc;
            av[i] += p * xc;
        }
    }
#pragma unroll
    for (int i = 0; i < 16; ++i) {
        int j = jb + 4 * i;
        size_t base = ((size_t)b * NPTS + n0 + j) * 64 + o;
        u[base] = au[i];                    // coalesced over o
        v[base] = av[i];
    }
}

// ---------------------------------------------------------------------------
// K1a (split path): distances ONLY -> D[b][m][n] fp32. No top-k state: the
// register working set (row4 64 + staging 16 + temps) fits arch VGPRs, which
// removes the AGPR shuttle tax that capped the fused kernel (R5/R7:
// VGPR_Count 76-84 proves row4 was parked in AGPRs; ~340 VALU inst/cand vs
// ~150 modeled). d expression bit-identical to the fused kernel.
// Candidate tiles LDS-staged (R5 structure). b = bid&7 = XCD id.
// Stores coalesced over n (lane = n).
// ---------------------------------------------------------------------------
__global__ __launch_bounds__(256, 2) void k_dist(const float* __restrict__ xT,
                                                 const float* __restrict__ xx,
                                                 float* __restrict__ D) {
    __shared__ float cb[TILE * 64];         // 64 cands x 64 ch = 16 KB
    __shared__ float xxs[SCH];              // 2 KB
    const int t = threadIdx.x;
    const int bid = blockIdx.x + 16 * (blockIdx.y + NSEL * blockIdx.z);
    const int b = bid & 7;                  // XCD id under hw round-robin
    const int rest = bid >> 3;              // 0..127
    const int chunk = rest & (NSEL - 1);    // 0..7
    const int rowgrp = rest >> 3;           // 0..15
    const int n = rowgrp * 256 + t;
    const int m0 = chunk * SCH;

    const float* xTb = xT + (size_t)b * NPTS * 64;

#pragma unroll
    for (int r = 0; r < SCH / 256; ++r)
        xxs[t + 256 * r] = xx[b * NPTS + m0 + t + 256 * r];

    float4 row4[16];
    const float4* rp = (const float4*)(xTb + (size_t)n * 64);
#pragma unroll
    for (int q = 0; q < 16; ++q) row4[q] = rp[q];

    // output base: D[(b*4096 + m)*4096 + n]
    float* Dp = D + ((size_t)b * NPTS + m0) * NPTS + n;

    // stage tile 0 into registers
    const float4* gt0 = (const float4*)(xTb + (size_t)m0 * 64);
    float4 st0 = gt0[t], st1 = gt0[t + 256], st2 = gt0[t + 512], st3 = gt0[t + 768];

    for (int T = 0; T < NTILE_A; ++T) {
        __syncthreads();                    // all waves done reading cb (tile T-1)
        ((float4*)cb)[t      ] = st0;       // publish tile T
        ((float4*)cb)[t + 256] = st1;
        ((float4*)cb)[t + 512] = st2;
        ((float4*)cb)[t + 768] = st3;
        __syncthreads();
        // per-tile pin: bound any AGPR parking of row4 to <=1 restore/cand
#pragma unroll
        for (int q = 0; q < 16; ++q) {
            asm volatile("" : "+v"(row4[q].x), "+v"(row4[q].y),
                              "+v"(row4[q].z), "+v"(row4[q].w));
        }
        // issue next tile's loads NOW; they complete during the compute phase
        int Tn = (T + 1 < NTILE_A) ? T + 1 : T;
        const float4* gn = (const float4*)(xTb + (size_t)(m0 + Tn * TILE) * 64);
        st0 = gn[t]; st1 = gn[t + 256]; st2 = gn[t + 512]; st3 = gn[t + 768];

        float* DT = Dp + (size_t)T * TILE * NPTS;
#pragma unroll 2
        for (int mm = 0; mm < TILE; ++mm) {
            const float4* cp = (const float4*)(cb + mm * 64);
            float4 acc = make_float4(0.f, 0.f, 0.f, 0.f);
#pragma unroll
            for (int q = 0; q < 16; ++q) {
                float4 c4 = cp[q];          // uniform addr -> LDS broadcast
                acc.x += row4[q].x * c4.x;
                acc.y += row4[q].y * c4.y;
                acc.z += row4[q].z * c4.z;
                acc.w += row4[q].w * c4.w;
            }
            float inner = (acc.x + acc.y) + (acc.z + acc.w);
            float d = 2.f * inner - xxs[T * TILE + mm];
            DT[(size_t)mm * NPTS] = d;      // coalesced over lanes (n)
        }
    }
}

// ---------------------------------------------------------------------------
// K1b (split path): selection ONLY. Thread = row, streams D[b][m][n] with
// lane = n (perfectly coalesced 256 B/wave loads, independent of the chain ->
// compiler pipelines them). Chain code/order identical to R5's passing
// version (bool array, med3 shift-insert) -> bit-identical top-20.
// Register need ~55 -> no AGPR risk.
// ---------------------------------------------------------------------------
__global__ __launch_bounds__(256, 4) void k_sel(const float* __restrict__ D,
                                                float* __restrict__ cval,
                                                int* __restrict__ cidx) {
    const int t = threadIdx.x;
    const int r = blockIdx.x * 256 + t;     // 0..B*N-1
    const int b = r >> 12;
    const int n = r & (NPTS - 1);
    const int chunk = blockIdx.y;           // 0..NSEL-1
    const int m0 = chunk * SCH;

    float vals[KNN];
    int   idxs[KNN];
#pragma unroll
    for (int k = 0; k < KNN; ++k) { vals[k] = -INFINITY; idxs[k] = -1; }

    const float* p = D + ((size_t)b * NPTS + m0) * NPTS + n;

#pragma unroll 4
    for (int mm = 0; mm < SCH; ++mm) {
        float d = p[(size_t)mm * NPTS];
        if (d > vals[KNN - 1]) {
            const int midx = m0 + mm;
            bool c[KNN];
#pragma unroll
            for (int k = 0; k < KNN; ++k) c[k] = (vals[k] >= d);  // old vals
#pragma unroll
            for (int j = KNN - 1; j >= 1; --j) {
                vals[j] = __builtin_amdgcn_fmed3f(d, vals[j - 1], vals[j]);
                idxs[j] = c[j] ? idxs[j] : (c[j - 1] ? midx : idxs[j - 1]);
            }
            vals[0] = fmaxf(vals[0], d);
            idxs[0] = c[0] ? idxs[0] : midx;
        }
    }

    size_t rbase = ((size_t)r * NSEL + chunk) * KNN;
#pragma unroll
    for (int k = 0; k < KNN; ++k) { cval[rbase + k] = vals[k]; cidx[rbase + k] = idxs[k]; }
}

// ---------------------------------------------------------------------------
// K1 (fused fallback, verbatim R5 = best fused config): used when ws_size
// cannot hold D. LDS-staged candidates, row4 pinned pre-loop, (256,2).
// ---------------------------------------------------------------------------
__global__ __launch_bounds__(256, 2) void k_knn(const float* __restrict__ xT,
                                                const float* __restrict__ xx,
                                                float* __restrict__ cval,
                                                int* __restrict__ cidx) {
    __shared__ float cb[TILE * 64];         // 64 cands x 64 ch = 16 KB
    __shared__ float xxs[CHUNK];            // 4 KB
    const int t = threadIdx.x;
    const int bid = blockIdx.x + 16 * (blockIdx.y + NCHUNK * blockIdx.z);
    const int b = bid & 7;                  // XCD id under hw round-robin
    const int slot = bid >> 3;              // 0..63
    const int chunk = slot & (NCHUNK - 1);  // 0..3
    const int rowgrp = slot >> 2;           // 0..15
    const int n = rowgrp * 256 + t;
    const int m0 = chunk * CHUNK;

    const float* xTb = xT + (size_t)b * NPTS * 64;

#pragma unroll
    for (int r = 0; r < 4; ++r)
        xxs[t + 256 * r] = xx[b * NPTS + m0 + t + 256 * r];

    float4 row4[16];
    const float4* rp = (const float4*)(xTb + (size_t)n * 64);
#pragma unroll
    for (int q = 0; q < 16; ++q) row4[q] = rp[q];
#pragma unroll
    for (int q = 0; q < 16; ++q) {
        asm volatile("" : "+v"(row4[q].x), "+v"(row4[q].y),
                          "+v"(row4[q].z), "+v"(row4[q].w));
    }

    float vals[KNN];
    int   idxs[KNN];
#pragma unroll
    for (int k = 0; k < KNN; ++k) { vals[k] = -INFINITY; idxs[k] = -1; }

    const float4* gt0 = (const float4*)(xTb + (size_t)m0 * 64);
    float4 st0 = gt0[t], st1 = gt0[t + 256], st2 = gt0[t + 512], st3 = gt0[t + 768];

    for (int T = 0; T < NTILE; ++T) {
        __syncthreads();
        ((float4*)cb)[t      ] = st0;
        ((float4*)cb)[t + 256] = st1;
        ((float4*)cb)[t + 512] = st2;
        ((float4*)cb)[t + 768] = st3;
        __syncthreads();
        int Tn = (T + 1 < NTILE) ? T + 1 : T;
        const float4* gn = (const float4*)(xTb + (size_t)(m0 + Tn * TILE) * 64);
        st0 = gn[t]; st1 = gn[t + 256]; st2 = gn[t + 512]; st3 = gn[t + 768];

#pragma unroll 2
        for (int mm = 0; mm < TILE; ++mm) {
            const float4* cp = (const float4*)(cb + mm * 64);
            float4 acc = make_float4(0.f, 0.f, 0.f, 0.f);
#pragma unroll
            for (int q = 0; q < 16; ++q) {
                float4 c4 = cp[q];
                acc.x += row4[q].x * c4.x;
                acc.y += row4[q].y * c4.y;
                acc.z += row4[q].z * c4.z;
                acc.w += row4[q].w * c4.w;
            }
            float inner = (acc.x + acc.y) + (acc.z + acc.w);
            float d = 2.f * inner - xxs[T * TILE + mm];
            const int midx = m0 + T * TILE + mm;
            if (d > vals[KNN - 1]) {
                bool c[KNN];
#pragma unroll
                for (int k = 0; k < KNN; ++k) c[k] = (vals[k] >= d);
#pragma unroll
                for (int j = KNN - 1; j >= 1; --j) {
                    vals[j] = __builtin_amdgcn_fmed3f(d, vals[j - 1], vals[j]);
                    idxs[j] = c[j] ? idxs[j] : (c[j - 1] ? midx : idxs[j - 1]);
                }
                vals[0] = fmaxf(vals[0], d);
                idxs[0] = c[0] ? idxs[0] : midx;
            }
        }
    }

    size_t rbase = ((size_t)(b * NPTS + n) * NCHUNK + chunk) * KNN;
#pragma unroll
    for (int k = 0; k < KNN; ++k) { cval[rbase + k] = vals[k]; cidx[rbase + k] = idxs[k]; }
}

// ---------------------------------------------------------------------------
// K2: NC-way merge of per-chunk sorted top-20 lists. Strict '>' keeps the
// lowest chunk on ties (chunks cover ascending m) = lowest-index-first.
// ---------------------------------------------------------------------------
template <int NC>
__global__ __launch_bounds__(256) void k_merge(const float* __restrict__ cval,
                                               const int* __restrict__ cidx,
                                               int* __restrict__ idxf) {
    const int r = blockIdx.x * 256 + threadIdx.x;   // 0..B*N-1
    const float* v0 = cval + (size_t)r * (NC * KNN);
    const int*   i0 = cidx + (size_t)r * (NC * KNN);
    int p[NC];
#pragma unroll
    for (int c = 0; c < NC; ++c) p[c] = 0;
    int* op = idxf + (size_t)r * KNN;
    for (int k = 0; k < KNN; ++k) {
        float best = -INFINITY; int besti = 0, bc = 0;
#pragma unroll
        for (int c = 0; c < NC; ++c) {
            float hv = v0[c * KNN + p[c]];          // L1-cached re-reads
            int   hi = i0[c * KNN + p[c]];
            bool g = hv > best;
            best = g ? hv : best;
            besti = g ? hi : besti;
            bc = g ? c : bc;
        }
        op[k] = besti;
#pragma unroll
        for (int c = 0; c < NC; ++c) p[c] += (bc == c);
    }
}

// ---------------------------------------------------------------------------
// K4: single gather pass: h = u[n][o] + v[m][o]; accumulate sum/sumsq per
// channel (block partials, no atomics -> deterministic) and per-(n,o) max/min.
// ---------------------------------------------------------------------------
__global__ __launch_bounds__(256) void k_gather(const float* __restrict__ u,
                                                const float* __restrict__ v,
                                                const int* __restrict__ idxf,
                                                float* __restrict__ hmax,
                                                float* __restrict__ hmin,
                                                float* __restrict__ part) {
    const int t = threadIdx.x;
    const int o = t & 63, w = t >> 6;
    const int b = blockIdx.y;
    const int n0 = blockIdx.x * 64;
    const float* vb = v + (size_t)b * NPTS * 64;
    float su = 0.f, sq = 0.f;
    for (int r = 0; r < 16; ++r) {
        int n = n0 + w + 4 * r;
        size_t nb = (size_t)b * NPTS + n;
        float hu = u[nb * 64 + o];
        const int* ip = idxf + nb * KNN;    // wave-uniform reads
        float mx = -INFINITY, mn = INFINITY;
#pragma unroll 4
        for (int k = 0; k < KNN; ++k) {
            int m = ip[k];
            float h = hu + vb[(size_t)m * 64 + o];
            mx = fmaxf(mx, h);
            mn = fminf(mn, h);
            su += h;
            sq += h * h;
        }
        hmax[nb * 64 + o] = mx;
        hmin[nb * 64 + o] = mn;
    }
    __shared__ float red[4][128];
    red[w][o] = su;
    red[w][64 + o] = sq;
    __syncthreads();
    if (t < 128) {
        float s = red[0][t] + red[1][t] + red[2][t] + red[3][t];
        part[(size_t)(blockIdx.y * 64 + blockIdx.x) * 128 + t] = s;
    }
}

// ---------------------------------------------------------------------------
// K5: reduce 512 block partials -> mean/var -> fused scale/shift.
// ---------------------------------------------------------------------------
__global__ __launch_bounds__(256) void k_stats(const float* __restrict__ part,
                                               const float* __restrict__ gamma,
                                               const float* __restrict__ beta,
                                               float* __restrict__ ab) {
    __shared__ float rs[4][64], rq[4][64];
    const int t = threadIdx.x;
    const int o = t & 63, sl = t >> 6;      // 4 slices of 128 rows
    float s = 0.f, q = 0.f;
    for (int r = sl; r < 512; r += 4) {
        s += part[r * 128 + o];
        q += part[r * 128 + 64 + o];
    }
    rs[sl][o] = s; rq[sl][o] = q;
    __syncthreads();
    if (t < 64) {
        float ss = rs[0][t] + rs[1][t] + rs[2][t] + rs[3][t];
        float qq = rq[0][t] + rq[1][t] + rq[2][t] + rq[3][t];
        const float cnt = (float)BATCH * NPTS * KNN;
        float mean = ss / cnt;
        float var = qq / cnt - mean * mean;
        float rstd = rsqrtf(var + 1e-5f);
        float a = gamma[t] * rstd;
        ab[t] = a;
        ab[64 + t] = beta[t] - mean * a;
    }
}

// ---------------------------------------------------------------------------
// K6: epilogue. Monotone affine+LeakyReLU => max over k is at hmax (scale>=0)
// or hmin (scale<0). LDS transpose for coalesced out[b][o][n] writes.
// ---------------------------------------------------------------------------
__global__ __launch_bounds__(256) void k_out(const float* __restrict__ hmax,
                                             const float* __restrict__ hmin,
                                             const float* __restrict__ ab,
                                             float* __restrict__ out) {
    __shared__ float ts[64][65];
    const int t = threadIdx.x;
    const int b = blockIdx.y;
    const int n0 = blockIdx.x * 64;
#pragma unroll
    for (int i = 0; i < 16; ++i) {
        int flat = t + 256 * i;
        int j = flat >> 6, o = flat & 63;
        size_t nb = ((size_t)b * NPTS + n0 + j) * 64 + o;
        float a = ab[o], sh = ab[64 + o];
        float hval = (a >= 0.f) ? hmax[nb] : hmin[nb];
        float val = a * hval + sh;
        val = (val >= 0.f) ? val : 0.2f * val;
        ts[o][j] = val;
    }
    __syncthreads();
#pragma unroll
    for (int i = 0; i < 16; ++i) {
        int flat = t + 256 * i;
        int o = flat >> 6, j = flat & 63;
        out[((size_t)b * 64 + o) * NPTS + n0 + j] = ts[o][j];
    }
}

// ---------------------------------------------------------------------------
extern "C" void kernel_launch(void* const* d_in, const int* in_sizes, int n_in,
                              void* d_out, int out_size, void* d_ws, size_t ws_size,
                              hipStream_t stream) {
    const float* x     = (const float*)d_in[0];   // (8, 64, 4096)
    const float* W     = (const float*)d_in[1];   // (64, 128)
    const float* gamma = (const float*)d_in[2];   // (64,)
    const float* beta  = (const float*)d_in[3];   // (64,)
    float* out = (float*)d_out;                   // (8, 64, 4096)

    float* ws = (float*)d_ws;
    const size_t BN = (size_t)BATCH * NPTS;       // 32768
    size_t off = 0;
    float* xT   = ws + off; off += BN * 64;
    float* xx   = ws + off; off += BN;
    float* u    = ws + off; off += BN * 64;
    float* v    = ws + off; off += BN * 64;
    float* cval = ws + off; off += BN * NSEL * KNN;   // sized for the larger (split) path
    int*   cidx = (int*)(ws + off); off += BN * NSEL * KNN;
    int*   idxf = (int*)(ws + off); off += BN * KNN;
    float* hmx  = ws + off; off += BN * 64;
    float* hmn  = ws + off; off += BN * 64;
    float* part = ws + off; off += 512 * 128;
    float* ab   = ws + off; off += 128;
    float* D    = ws + off;                       // distance matrix, split path only
    const size_t need_split = (off + BN * (size_t)NPTS) * sizeof(float); // ~624 MB
    const bool split = (ws_size >= need_split);   // ws_size is call-invariant ->
                                                  // same work every call
    k_prep<<<dim3(64, BATCH), 256, 0, stream>>>(x, W, xT, xx, u, v);
    if (split) {
        k_dist<<<dim3(16, NSEL, BATCH), 256, 0, stream>>>(xT, xx, D);
        k_sel <<<dim3((int)(BN / 256), NSEL), 256, 0, stream>>>(D, cval, cidx);
        k_merge<NSEL><<<dim3((int)(BN / 256)), 256, 0, stream>>>(cval, cidx, idxf);
    } else {
        k_knn<<<dim3(16, NCHUNK, BATCH), 256, 0, stream>>>(xT, xx, cval, cidx);
        k_merge<NCHUNK><<<dim3((int)(BN / 256)), 256, 0, stream>>>(cval, cidx, idxf);
    }
    k_gather<<<dim3(64, BATCH), 256, 0, stream>>>(u, v, idxf, hmx, hmn, part);
    k_stats<<<1, 256, 0, stream>>>(part, gamma, beta, ab);
    k_out  <<<dim3(64, BATCH), 256, 0, stream>>>(hmx, hmn, ab, out);
}